// Round 10
// baseline (109.570 us; speedup 1.0000x reference)
//
#include <hip/hip_runtime.h>

typedef __bf16 bf16x8 __attribute__((ext_vector_type(8)));
typedef float f32x4 __attribute__((ext_vector_type(4)));
typedef unsigned short u16x8 __attribute__((ext_vector_type(8)));
typedef unsigned short u16x4 __attribute__((ext_vector_type(4)));

#define B_ 32
#define CC 512
#define HW 192
#define C8_ 64
#define NTRI 528
#define NBLK 656          // 528 gram + 128 pam
#define PAIR_B 24576      // one buffer: A(192x32) + B(192x32) bf16, 64B rows
#define SMEM_BYTES 73728  // 3 buffers; epilogue/pam bufs alias

__device__ inline unsigned short f2bf(float f) {
    unsigned u = __float_as_uint(f);
    unsigned r = (u + 0x7FFFu + ((u >> 16) & 1u)) >> 16;
    return (unsigned short)r;
}

__device__ inline void gload16(const void* g, void* l) {
    __builtin_amdgcn_global_load_lds(
        (const __attribute__((address_space(1))) unsigned*)g,
        (__attribute__((address_space(3))) unsigned*)l,
        16, 0, 0);
}

// ---------------- Kernel 1 (fused prep): transpose + weight precast ---------
// grid (104, 8) x 256 thr. x<96: 64m x 64c transpose tile; x>=96: wcvt.
__global__ void prep(const float* __restrict__ x,
                     const float* __restrict__ Wq, const float* __restrict__ Wk,
                     unsigned short* __restrict__ xt,
                     unsigned short* __restrict__ wqb, unsigned short* __restrict__ wkb) {
    __shared__ unsigned short tile[64 * 64];
    int t = threadIdx.x;
    if (blockIdx.x >= 96) {
        int id = (blockIdx.x - 96) * 8 + blockIdx.y;     // 0..63
        const float* src = (id < 32) ? Wq : Wk;
        unsigned short* dst = (id < 32) ? wqb : wkb;
        int base = (id & 31) * 1024 + t * 4;
        f32x4 a = *(const f32x4*)(src + base);
        u16x4 o;
        #pragma unroll
        for (int e = 0; e < 4; ++e) o[e] = f2bf(a[e]);
        *(u16x4*)(dst + base) = o;
        return;
    }
    int b = blockIdx.x / 3, mt = blockIdx.x % 3;
    int m0 = mt * 64, c0 = blockIdx.y * 64;
    const float* xb = x + (size_t)b * CC * HW + (size_t)c0 * HW + m0;

    int mq = t & 15, cl0 = t >> 4;
    int sw = (mq & 7) << 3;
    #pragma unroll
    for (int rd = 0; rd < 4; ++rd) {
        int cl = rd * 16 + cl0;
        f32x4 v = *(const f32x4*)(xb + cl * HW + mq * 4);
        #pragma unroll
        for (int e = 0; e < 4; ++e)
            tile[(mq * 4 + e) * 64 + (cl ^ sw)] = f2bf(v[e]);
    }
    __syncthreads();
    unsigned short* xo = xt + ((size_t)b * HW + m0) * CC + c0;
    int kc = t & 7, mr0 = t >> 3;
    #pragma unroll
    for (int rd = 0; rd < 2; ++rd) {
        int mr = rd * 32 + mr0;
        u16x8 v = *(const u16x8*)&tile[mr * 64 + ((kc << 3) ^ (((mr >> 2) & 7) << 3))];
        *(u16x8*)(xo + (size_t)mr * CC + kc * 8) = v;
    }
}

// ---------------- Kernel 2 (fused): gram (bids 0..527) + PAM (528..655) -----
__global__ __launch_bounds__(512, 4) void gram_pam(
        const unsigned short* __restrict__ xt,
        const unsigned short* __restrict__ wqb, const unsigned short* __restrict__ wkb,
        const float* __restrict__ bq, const float* __restrict__ bk,
        float* __restrict__ out) {
    extern __shared__ char smem[];
    int tid = threadIdx.x;
    int w = tid >> 6, lane = tid & 63;
    int l15 = lane & 15, lq = lane >> 4;
    int bid = (blockIdx.x & 7) * 82 + (blockIdx.x >> 3);   // 656 = 8*82

    if (bid < NTRI) {
        // ================= GRAM (round-9 verbatim) =================
        int idx = bid, g = 0;
        while (idx >= B_ - g) { idx -= B_ - g; ++g; }
        int p = g + idx;
        const unsigned short* xg = xt + (size_t)g * HW * CC;
        const unsigned short* xp = xt + (size_t)p * HW * CC;
        int wr = w >> 2, wc = w & 3;

        int rowbase = (w & 3) * 48;
        const unsigned short* gsrc = (w < 4 ? xg : xp)
            + (size_t)(rowbase + (lane >> 2)) * CC
            + (((lane & 3) ^ ((lane >> 3) & 3)) << 3);
        unsigned ldsoff = (unsigned)(w < 4 ? 0 : 12288) + (unsigned)rowbase * 64;

        unsigned ssw = (unsigned)((lq ^ ((l15 >> 1) & 3)) << 4);
        unsigned aoff[6], boff[3];
        #pragma unroll
        for (int i = 0; i < 6; ++i)
            aoff[i] = (unsigned)(wr * 96 + i * 16 + l15) * 64 + ssw;
        #pragma unroll
        for (int j = 0; j < 3; ++j)
            boff[j] = 12288u + (unsigned)(wc * 48 + j * 16 + l15) * 64 + ssw;

        f32x4 acc[6][3];
        #pragma unroll
        for (int i = 0; i < 6; ++i)
            #pragma unroll
            for (int j = 0; j < 3; ++j)
                acc[i][j] = (f32x4){0.f, 0.f, 0.f, 0.f};

        #define STAGE(buf, kt)                                                 \
            {                                                                  \
                char* db = smem + (buf) * PAIR_B + ldsoff;                     \
                const unsigned short* gp = gsrc + (kt) * 32;                   \
                _Pragma("unroll")                                              \
                for (int ci = 0; ci < 3; ++ci)                                 \
                    gload16(gp + ci * 16 * CC, db + ci * 1024);                \
            }

        #define COMPUTE(buf)                                                   \
            {                                                                  \
                const char* Bb = smem + (buf) * PAIR_B;                        \
                bf16x8 af[6], bfr[3];                                          \
                _Pragma("unroll")                                              \
                for (int i = 0; i < 6; ++i)                                    \
                    af[i] = *(const bf16x8*)(Bb + aoff[i]);                    \
                _Pragma("unroll")                                              \
                for (int j = 0; j < 3; ++j)                                    \
                    bfr[j] = *(const bf16x8*)(Bb + boff[j]);                   \
                _Pragma("unroll")                                              \
                for (int i = 0; i < 6; ++i)                                    \
                    _Pragma("unroll")                                          \
                    for (int j = 0; j < 3; ++j)                                \
                        acc[i][j] = __builtin_amdgcn_mfma_f32_16x16x32_bf16(   \
                            af[i], bfr[j], acc[i][j], 0, 0, 0);                \
            }

        #define WAIT3() asm volatile("s_waitcnt vmcnt(3)" ::: "memory")
        #define WAIT0() asm volatile("s_waitcnt vmcnt(0)" ::: "memory")
        #define BAR()   { __builtin_amdgcn_sched_barrier(0); __builtin_amdgcn_s_barrier(); }

        STAGE(0, 0);
        STAGE(1, 1);

        #pragma unroll
        for (int kt = 0; kt < 16; ++kt) {
            if (kt < 15) { WAIT3(); } else { WAIT0(); }
            BAR();
            if (kt < 14) STAGE((kt + 2) % 3, kt + 2);
            COMPUTE(kt % 3);
        }

        float* colbuf = (float*)(smem + PAIR_B);          // [2][192]
        float* rowbuf = colbuf + 2 * HW;                  // [4][192]
        #pragma unroll
        for (int j = 0; j < 3; ++j) {
            float cm = -1e30f;
            #pragma unroll
            for (int i = 0; i < 6; ++i)
                #pragma unroll
                for (int r = 0; r < 4; ++r)
                    cm = fmaxf(cm, acc[i][j][r]);
            cm = fmaxf(cm, __shfl_xor(cm, 16));
            cm = fmaxf(cm, __shfl_xor(cm, 32));
            if (lane < 16) colbuf[wr * HW + wc * 48 + j * 16 + l15] = cm;
        }
        #pragma unroll
        for (int i = 0; i < 6; ++i) {
            float rm[4];
            #pragma unroll
            for (int r = 0; r < 4; ++r) rm[r] = -1e30f;
            #pragma unroll
            for (int j = 0; j < 3; ++j)
                #pragma unroll
                for (int r = 0; r < 4; ++r)
                    rm[r] = fmaxf(rm[r], acc[i][j][r]);
            #pragma unroll
            for (int msk = 1; msk <= 8; msk <<= 1)
                #pragma unroll
                for (int r = 0; r < 4; ++r)
                    rm[r] = fmaxf(rm[r], __shfl_xor(rm[r], msk));
            if (l15 == 0) {
                #pragma unroll
                for (int r = 0; r < 4; ++r)
                    rowbuf[wc * HW + wr * 96 + i * 16 + lq * 4 + r] = rm[r];
            }
        }
        __syncthreads();
        if (tid < HW) {
            float cmax = fmaxf(colbuf[tid], colbuf[HW + tid]);
            out[((size_t)g * B_ + p) * HW + tid] = cmax;
            float rmax = fmaxf(fmaxf(rowbuf[tid], rowbuf[HW + tid]),
                               fmaxf(rowbuf[2 * HW + tid], rowbuf[3 * HW + tid]));
            out[((size_t)p * B_ + g) * HW + tid] = rmax;
        }
    } else {
        // ================= PAM (block = (b, mgrp)) =================
        int pb = bid - NTRI;                   // 0..127
        int b = pb >> 2, mgrp = pb & 3;
        int m0 = mgrp * 48;
        unsigned short* qs = (unsigned short*)smem;            // [48][64] swz
        unsigned short* ks = (unsigned short*)(smem + 6144);   // [192][64] swz
        float* red = (float*)(smem + 6144 + 24576);            // [8][48]
        const unsigned short* xb = xt + (size_t)b * HW * CC;

        int qc = (w & 3) * 16 + l15;
        if (w < 4) {
            // q projection: rows m0..m0+47, col-frag w
            const unsigned short* wp = wqb + (size_t)qc * CC;
            float bias = bq[qc];
            f32x4 a3[3];
            #pragma unroll
            for (int i = 0; i < 3; ++i) a3[i] = (f32x4){0.f, 0.f, 0.f, 0.f};
            for (int kt = 0; kt < 16; ++kt) {
                int ko8 = kt * 32 + lq * 8;
                bf16x8 wf = *(const bf16x8*)(wp + ko8);
                #pragma unroll
                for (int i = 0; i < 3; ++i) {
                    bf16x8 af = *(const bf16x8*)(xb + (m0 + i * 16 + l15) * CC + ko8);
                    a3[i] = __builtin_amdgcn_mfma_f32_16x16x32_bf16(af, wf, a3[i], 0, 0, 0);
                }
            }
            #pragma unroll
            for (int i = 0; i < 3; ++i) {
                #pragma unroll
                for (int r = 0; r < 4; ++r) {
                    int lm = i * 16 + lq * 4 + r;
                    qs[lm * 64 + ((((qc >> 3) ^ (lm & 7)) << 3) | (qc & 7))] = f2bf(a3[i][r] + bias);
                }
            }
        } else {
            // k projection: ALL 192 rows, col-frag w-4
            const unsigned short* wp = wkb + (size_t)qc * CC;
            float bias = bk[qc];
            f32x4 kacc[12];
            #pragma unroll
            for (int i = 0; i < 12; ++i) kacc[i] = (f32x4){0.f, 0.f, 0.f, 0.f};
            for (int kt = 0; kt < 16; ++kt) {
                int ko8 = kt * 32 + lq * 8;
                bf16x8 wf = *(const bf16x8*)(wp + ko8);
                #pragma unroll
                for (int i = 0; i < 12; ++i) {
                    bf16x8 af = *(const bf16x8*)(xb + (i * 16 + l15) * CC + ko8);
                    kacc[i] = __builtin_amdgcn_mfma_f32_16x16x32_bf16(af, wf, kacc[i], 0, 0, 0);
                }
            }
            #pragma unroll
            for (int i = 0; i < 12; ++i) {
                #pragma unroll
                for (int r = 0; r < 4; ++r) {
                    int m = i * 16 + lq * 4 + r;
                    ks[m * 64 + ((((qc >> 3) ^ (m & 7)) << 3) | (qc & 7))] = f2bf(kacc[i][r] + bias);
                }
            }
        }
        __syncthreads();

        // energy = q k^T for rows m0..m0+47, all 192 n; fused row-max over n.
        // waves 0-3: n-frags {2w, 2w+1}; waves 4-7: n-frag {8+(w-4)}.
        int nf0 = (w < 4) ? 2 * w : 8 + (w - 4);
        int nfn = (w < 4) ? 2 : 1;
        f32x4 acc2[3][2];
        #pragma unroll
        for (int i = 0; i < 3; ++i)
            #pragma unroll
            for (int j = 0; j < 2; ++j)
                acc2[i][j] = (f32x4){0.f, 0.f, 0.f, 0.f};
        #pragma unroll
        for (int kt2 = 0; kt2 < 2; ++kt2) {
            int chunk = kt2 * 4 + lq;
            bf16x8 af[3];
            #pragma unroll
            for (int i = 0; i < 3; ++i) {
                int lm = i * 16 + l15;
                af[i] = *(const bf16x8*)&qs[lm * 64 + ((chunk ^ (lm & 7)) << 3)];
            }
            #pragma unroll
            for (int jj = 0; jj < 2; ++jj) {
                if (jj < nfn) {
                    int n = (nf0 + jj) * 16 + l15;
                    bf16x8 bfr = *(const bf16x8*)&ks[n * 64 + ((chunk ^ (n & 7)) << 3)];
                    #pragma unroll
                    for (int i = 0; i < 3; ++i)
                        acc2[i][jj] = __builtin_amdgcn_mfma_f32_16x16x32_bf16(
                            af[i], bfr, acc2[i][jj], 0, 0, 0);
                }
            }
        }
        #pragma unroll
        for (int i = 0; i < 3; ++i) {
            float rm[4];
            #pragma unroll
            for (int r = 0; r < 4; ++r) rm[r] = -1e30f;
            #pragma unroll
            for (int jj = 0; jj < 2; ++jj)
                if (jj < nfn)
                    #pragma unroll
                    for (int r = 0; r < 4; ++r)
                        rm[r] = fmaxf(rm[r], acc2[i][jj][r]);
            #pragma unroll
            for (int msk = 1; msk <= 8; msk <<= 1)
                #pragma unroll
                for (int r = 0; r < 4; ++r)
                    rm[r] = fmaxf(rm[r], __shfl_xor(rm[r], msk));
            if (l15 == 0) {
                #pragma unroll
                for (int r = 0; r < 4; ++r)
                    red[w * 48 + i * 16 + lq * 4 + r] = rm[r];
            }
        }
        __syncthreads();
        if (tid < 48) {
            float v = red[tid];
            #pragma unroll
            for (int ww = 1; ww < 8; ++ww)
                v = fmaxf(v, red[ww * 48 + tid]);
            out[((size_t)B_ * B_ + b) * HW + m0 + tid] = v;
        }
    }
}

extern "C" void kernel_launch(void* const* d_in, const int* in_sizes, int n_in,
                              void* d_out, int out_size, void* d_ws, size_t ws_size,
                              hipStream_t stream) {
    (void)in_sizes; (void)n_in; (void)out_size; (void)ws_size;
    const float* x  = (const float*)d_in[0];
    const float* Wq = (const float*)d_in[1];
    const float* bq = (const float*)d_in[2];
    const float* Wk = (const float*)d_in[3];
    const float* bk = (const float*)d_in[4];
    float* out = (float*)d_out;

    char* ws = (char*)d_ws;
    unsigned short* xt  = (unsigned short*)ws;                       // 6291456 B
    unsigned short* wqb = (unsigned short*)(ws + 6291456);           // 65536 B
    unsigned short* wkb = (unsigned short*)(ws + 6291456 + 65536);   // 65536 B

    hipFuncSetAttribute((const void*)gram_pam,
                        hipFuncAttributeMaxDynamicSharedMemorySize, SMEM_BYTES);

    prep<<<dim3(104, 8), dim3(256), 0, stream>>>(x, Wq, Wk, xt, wqb, wkb);
    gram_pam<<<dim3(NBLK), dim3(512), SMEM_BYTES, stream>>>(xt, wqb, wkb, bq, bk, out);
}

// Round 11
// 56.384 us; speedup vs baseline: 1.9433x; 1.9433x over previous
//
#include <hip/hip_runtime.h>

typedef __bf16 bf16x8 __attribute__((ext_vector_type(8)));
typedef float f32x4 __attribute__((ext_vector_type(4)));
typedef unsigned short u16x8 __attribute__((ext_vector_type(8)));
typedef unsigned short u16x4 __attribute__((ext_vector_type(4)));

#define B_ 32
#define CC 512
#define HW 192
#define C8_ 64
#define NTRI 528
#define NG2 1056          // 2 half-tiles per pair
#define BUF_B 36864       // one buffer: A(96x64) + B(192x64) bf16, 128B rows
#define SMEM_BYTES 73728  // 2 buffers

__device__ inline unsigned short f2bf(float f) {
    unsigned u = __float_as_uint(f);
    unsigned r = (u + 0x7FFFu + ((u >> 16) & 1u)) >> 16;
    return (unsigned short)r;
}

__device__ inline void gload16(const void* g, void* l) {
    __builtin_amdgcn_global_load_lds(
        (const __attribute__((address_space(1))) unsigned*)g,
        (__attribute__((address_space(3))) unsigned*)l,
        16, 0, 0);
}

// ---------------- Kernel 1 (fused prep): transpose + weight precast ---------
__global__ void prep(const float* __restrict__ x,
                     const float* __restrict__ Wq, const float* __restrict__ Wk,
                     unsigned short* __restrict__ xt,
                     unsigned short* __restrict__ wqb, unsigned short* __restrict__ wkb) {
    __shared__ unsigned short tile[64 * 64];
    int t = threadIdx.x;
    if (blockIdx.x >= 96) {
        int id = (blockIdx.x - 96) * 8 + blockIdx.y;     // 0..63
        const float* src = (id < 32) ? Wq : Wk;
        unsigned short* dst = (id < 32) ? wqb : wkb;
        int base = (id & 31) * 1024 + t * 4;
        f32x4 a = *(const f32x4*)(src + base);
        u16x4 o;
        #pragma unroll
        for (int e = 0; e < 4; ++e) o[e] = f2bf(a[e]);
        *(u16x4*)(dst + base) = o;
        return;
    }
    int b = blockIdx.x / 3, mt = blockIdx.x % 3;
    int m0 = mt * 64, c0 = blockIdx.y * 64;
    const float* xb = x + (size_t)b * CC * HW + (size_t)c0 * HW + m0;

    int mq = t & 15, cl0 = t >> 4;
    int sw = (mq & 7) << 3;
    #pragma unroll
    for (int rd = 0; rd < 4; ++rd) {
        int cl = rd * 16 + cl0;
        f32x4 v = *(const f32x4*)(xb + cl * HW + mq * 4);
        #pragma unroll
        for (int e = 0; e < 4; ++e)
            tile[(mq * 4 + e) * 64 + (cl ^ sw)] = f2bf(v[e]);
    }
    __syncthreads();
    unsigned short* xo = xt + ((size_t)b * HW + m0) * CC + c0;
    int kc = t & 7, mr0 = t >> 3;
    #pragma unroll
    for (int rd = 0; rd < 2; ++rd) {
        int mr = rd * 32 + mr0;
        u16x8 v = *(const u16x8*)&tile[mr * 64 + ((kc << 3) ^ (((mr >> 2) & 7) << 3))];
        *(u16x8*)(xo + (size_t)mr * CC + kc * 8) = v;
    }
}

// ---------------- Kernel 2: q/k projections via MFMA (round-7 verbatim) -----
__global__ __launch_bounds__(256) void pam_qk(
        const unsigned short* __restrict__ xt,
        const unsigned short* __restrict__ wqb, const unsigned short* __restrict__ wkb,
        const float* __restrict__ bq, const float* __restrict__ bk,
        unsigned short* __restrict__ qo, unsigned short* __restrict__ ko) {
    int b = blockIdx.x, m0 = blockIdx.y * 48;
    int tid = threadIdx.x, w = tid >> 6, lane = tid & 63;
    int l15 = lane & 15, lq = lane >> 4;
    int qc = w * 16 + l15;

    f32x4 accq[3], acck[3];
    #pragma unroll
    for (int i = 0; i < 3; ++i) {
        accq[i] = (f32x4){0.f, 0.f, 0.f, 0.f};
        acck[i] = (f32x4){0.f, 0.f, 0.f, 0.f};
    }

    const unsigned short* xb = xt + ((size_t)b * HW + m0) * CC;
    const unsigned short* wqp = wqb + (size_t)qc * CC;
    const unsigned short* wkp = wkb + (size_t)qc * CC;

    for (int kt = 0; kt < 16; ++kt) {
        int ko8 = kt * 32 + lq * 8;
        bf16x8 wqf = *(const bf16x8*)(wqp + ko8);
        bf16x8 wkf = *(const bf16x8*)(wkp + ko8);
        bf16x8 af[3];
        #pragma unroll
        for (int i = 0; i < 3; ++i)
            af[i] = *(const bf16x8*)(xb + (i * 16 + l15) * CC + ko8);
        #pragma unroll
        for (int i = 0; i < 3; ++i) {
            accq[i] = __builtin_amdgcn_mfma_f32_16x16x32_bf16(af[i], wqf, accq[i], 0, 0, 0);
            acck[i] = __builtin_amdgcn_mfma_f32_16x16x32_bf16(af[i], wkf, acck[i], 0, 0, 0);
        }
    }

    float bqv = bq[qc], bkv = bk[qc];
    #pragma unroll
    for (int i = 0; i < 3; ++i) {
        #pragma unroll
        for (int r = 0; r < 4; ++r) {
            int m = m0 + i * 16 + lq * 4 + r;
            qo[((size_t)b * HW + m) * C8_ + qc] = f2bf(accq[i][r] + bqv);
            ko[((size_t)b * HW + m) * C8_ + qc] = f2bf(acck[i][r] + bkv);
        }
    }
}

// ---------------- Kernel 3: Gram half-tiles (96x192), 2 blocks/CU -----------
// 1056 blocks x 512 thr (8 waves, 2x4 of 48x48). BK=64, dbuf, drain barriers.
// Rowmax (full) -> out[p][g][96h+m]; colmax partial -> ws2[pair][h][n].
__global__ __launch_bounds__(512, 4) void gram2(const unsigned short* __restrict__ xt,
                                                float* __restrict__ out,
                                                float* __restrict__ ws2) {
    extern __shared__ char smem[];

    int tid = threadIdx.x;
    int bid = (blockIdx.x & 7) * 132 + (blockIdx.x >> 3);   // 1056 = 8*132
    int pairid = bid >> 1, h = bid & 1;
    int idx = pairid, g = 0;
    while (idx >= B_ - g) { idx -= B_ - g; ++g; }
    int p = g + idx;

    const unsigned short* xga = xt + ((size_t)g * HW + 96 * h) * CC;  // A: 96 rows
    const unsigned short* xp  = xt + (size_t)p * HW * CC;             // B: 192 rows

    int w = tid >> 6, lane = tid & 63;
    int wr = w >> 2, wc = w & 3;                // 2 x 4 wave grid
    int l15 = lane & 15, lq = lane >> 4;

    // ---- staging descriptors: chunk q (16B) -> lds byte q*16 (linear).
    // q<768: A row r=q>>3, slot s=q&7; else B row n=(q-768)>>3.
    // global src fetches logical chunk s^(row&7)  (inverse of read swizzle).
    const unsigned short* sp[5];
    unsigned lo[5];
    #pragma unroll
    for (int ci = 0; ci < 5; ++ci) {
        int R = (ci < 4) ? (w + 8 * ci) : (32 + w);
        int q = R * 64 + lane;
        if (ci == 4 && w >= 4) q = lane;        // dummy (unused)
        lo[ci] = (unsigned)q * 16;
        if (q < 768) {
            int r = q >> 3, s = q & 7;
            sp[ci] = xga + r * CC + ((s ^ (r & 7)) << 3);
        } else {
            int q2 = q - 768, n = q2 >> 3, s = q2 & 7;
            sp[ci] = xp + n * CC + ((s ^ (n & 7)) << 3);
        }
    }

    // ---- read offsets
    unsigned aoff[3], boff[3];
    #pragma unroll
    for (int i = 0; i < 3; ++i) {
        int row = wr * 48 + i * 16 + l15;                    // 0..95
        aoff[i] = (unsigned)row * 128 + ((unsigned)(lq ^ (row & 7)) << 4);
    }
    #pragma unroll
    for (int j = 0; j < 3; ++j) {
        int n = wc * 48 + j * 16 + l15;                      // 0..191
        boff[j] = 12288u + (unsigned)n * 128 + ((unsigned)(lq ^ (n & 7)) << 4);
    }

    f32x4 acc[3][3];
    #pragma unroll
    for (int i = 0; i < 3; ++i)
        #pragma unroll
        for (int j = 0; j < 3; ++j)
            acc[i][j] = (f32x4){0.f, 0.f, 0.f, 0.f};

    #define STG2(buf, kt)                                                      \
        {                                                                      \
            char* base = smem + (buf) * BUF_B;                                 \
            int k0 = (kt) * 64;                                                \
            gload16(sp[0] + k0, base + lo[0]);                                 \
            gload16(sp[1] + k0, base + lo[1]);                                 \
            gload16(sp[2] + k0, base + lo[2]);                                 \
            gload16(sp[3] + k0, base + lo[3]);                                 \
            if (w < 4) gload16(sp[4] + k0, base + lo[4]);                      \
        }

    #define CMP2(buf)                                                          \
        {                                                                      \
            const char* Bb = smem + (buf) * BUF_B;                             \
            _Pragma("unroll")                                                  \
            for (int kx = 0; kx < 128; kx += 64) {                             \
                bf16x8 af[3], bfr[3];                                          \
                _Pragma("unroll")                                              \
                for (int i = 0; i < 3; ++i)                                    \
                    af[i] = *(const bf16x8*)(Bb + (aoff[i] ^ kx));             \
                _Pragma("unroll")                                              \
                for (int j = 0; j < 3; ++j)                                    \
                    bfr[j] = *(const bf16x8*)(Bb + (boff[j] ^ kx));            \
                _Pragma("unroll")                                              \
                for (int i = 0; i < 3; ++i)                                    \
                    _Pragma("unroll")                                          \
                    for (int j = 0; j < 3; ++j)                                \
                        acc[i][j] = __builtin_amdgcn_mfma_f32_16x16x32_bf16(   \
                            af[i], bfr[j], acc[i][j], 0, 0, 0);                \
            }                                                                  \
        }

    STG2(0, 0);
    __syncthreads();
    for (int kt = 0; kt < 8; ++kt) {
        int cur = kt & 1;
        if (kt < 7) STG2(cur ^ 1, kt + 1);
        CMP2(cur);
        __syncthreads();
    }

    // ---- epilogue (buffers reusable after final sync)
    float* rowbuf = (float*)smem;            // [4][96]
    float* colbuf = (float*)(smem + 1536);   // [2][192]

    #pragma unroll
    for (int i = 0; i < 3; ++i) {            // rowmax over n (full 192)
        float rm[4];
        #pragma unroll
        for (int r = 0; r < 4; ++r) rm[r] = -1e30f;
        #pragma unroll
        for (int j = 0; j < 3; ++j)
            #pragma unroll
            for (int r = 0; r < 4; ++r)
                rm[r] = fmaxf(rm[r], acc[i][j][r]);
        #pragma unroll
        for (int msk = 1; msk <= 8; msk <<= 1)
            #pragma unroll
            for (int r = 0; r < 4; ++r)
                rm[r] = fmaxf(rm[r], __shfl_xor(rm[r], msk));
        if (l15 == 0) {
            #pragma unroll
            for (int r = 0; r < 4; ++r)
                rowbuf[wc * 96 + wr * 48 + i * 16 + lq * 4 + r] = rm[r];
        }
    }
    #pragma unroll
    for (int j = 0; j < 3; ++j) {            // colmax over m (96 rows, partial)
        float cm = -1e30f;
        #pragma unroll
        for (int i = 0; i < 3; ++i)
            #pragma unroll
            for (int r = 0; r < 4; ++r)
                cm = fmaxf(cm, acc[i][j][r]);
        cm = fmaxf(cm, __shfl_xor(cm, 16));
        cm = fmaxf(cm, __shfl_xor(cm, 32));
        if (lane < 16) colbuf[wr * HW + wc * 48 + j * 16 + l15] = cm;
    }
    __syncthreads();
    if (tid < 96) {
        float v = fmaxf(fmaxf(rowbuf[tid], rowbuf[96 + tid]),
                        fmaxf(rowbuf[192 + tid], rowbuf[288 + tid]));
        out[((size_t)p * B_ + g) * HW + 96 * h + tid] = v;
    }
    if (tid >= 128 && tid < 320) {
        int n = tid - 128;
        ws2[(size_t)pairid * 384 + h * 192 + n] = fmaxf(colbuf[n], colbuf[HW + n]);
    }
}

// ---------------- Kernel 4 (fused): pam_energy (0..127) + finalize (128..655)
__global__ __launch_bounds__(256) void energy_fin(
        const unsigned short* __restrict__ qo,
        const unsigned short* __restrict__ ko,
        const float* __restrict__ ws2,
        float* __restrict__ out) {
    int tid = threadIdx.x;
    if (blockIdx.x >= 128) {
        int pairid = blockIdx.x - 128;
        int idx = pairid, g = 0;
        while (idx >= B_ - g) { idx -= B_ - g; ++g; }
        int p = g + idx;
        if (tid < HW)
            out[((size_t)g * B_ + p) * HW + tid] =
                fmaxf(ws2[(size_t)pairid * 384 + tid], ws2[(size_t)pairid * 384 + 192 + tid]);
        return;
    }
    int b = blockIdx.x >> 2, m0 = (blockIdx.x & 3) * 48;
    int w = tid >> 6, lane = tid & 63;
    int l15 = lane & 15, lq = lane >> 4;
    int n0 = w * 48;

    f32x4 acc[3][3];
    #pragma unroll
    for (int i = 0; i < 3; ++i)
        #pragma unroll
        for (int j = 0; j < 3; ++j)
            acc[i][j] = (f32x4){0.f, 0.f, 0.f, 0.f};

    const unsigned short* qb = qo + ((size_t)b * HW + m0) * C8_;
    const unsigned short* kb = ko + ((size_t)b * HW + n0) * C8_;

    #pragma unroll
    for (int kt = 0; kt < 2; ++kt) {
        int ko8 = kt * 32 + lq * 8;
        bf16x8 af[3], bfr[3];
        #pragma unroll
        for (int i = 0; i < 3; ++i)
            af[i] = *(const bf16x8*)(qb + (i * 16 + l15) * C8_ + ko8);
        #pragma unroll
        for (int j = 0; j < 3; ++j)
            bfr[j] = *(const bf16x8*)(kb + (j * 16 + l15) * C8_ + ko8);
        #pragma unroll
        for (int i = 0; i < 3; ++i)
            #pragma unroll
            for (int j = 0; j < 3; ++j)
                acc[i][j] = __builtin_amdgcn_mfma_f32_16x16x32_bf16(af[i], bfr[j], acc[i][j], 0, 0, 0);
    }

    __shared__ float red[4][48];
    #pragma unroll
    for (int i = 0; i < 3; ++i) {
        float rm[4];
        #pragma unroll
        for (int r = 0; r < 4; ++r) rm[r] = -1e30f;
        #pragma unroll
        for (int j = 0; j < 3; ++j)
            #pragma unroll
            for (int r = 0; r < 4; ++r)
                rm[r] = fmaxf(rm[r], acc[i][j][r]);
        #pragma unroll
        for (int msk = 1; msk <= 8; msk <<= 1)
            #pragma unroll
            for (int r = 0; r < 4; ++r)
                rm[r] = fmaxf(rm[r], __shfl_xor(rm[r], msk));
        if (l15 == 0) {
            #pragma unroll
            for (int r = 0; r < 4; ++r)
                red[w][i * 16 + lq * 4 + r] = rm[r];
        }
    }
    __syncthreads();
    if (tid < 48) {
        float v = fmaxf(fmaxf(red[0][tid], red[1][tid]),
                        fmaxf(red[2][tid], red[3][tid]));
        out[((size_t)B_ * B_ + b) * HW + m0 + tid] = v;
    }
}

extern "C" void kernel_launch(void* const* d_in, const int* in_sizes, int n_in,
                              void* d_out, int out_size, void* d_ws, size_t ws_size,
                              hipStream_t stream) {
    (void)in_sizes; (void)n_in; (void)out_size; (void)ws_size;
    const float* x  = (const float*)d_in[0];
    const float* Wq = (const float*)d_in[1];
    const float* bq = (const float*)d_in[2];
    const float* Wk = (const float*)d_in[3];
    const float* bk = (const float*)d_in[4];
    float* out = (float*)d_out;

    char* ws = (char*)d_ws;
    unsigned short* xt  = (unsigned short*)ws;                        // 6291456 B
    unsigned short* wqb = (unsigned short*)(ws + 6291456);            // 65536 B
    unsigned short* wkb = (unsigned short*)(ws + 6291456 + 65536);    // 65536 B
    unsigned short* qbuf = (unsigned short*)(ws + 6291456 + 131072);  // 786432 B
    unsigned short* kbuf = (unsigned short*)(ws + 6291456 + 131072 + 786432);
    float* ws2 = (float*)(ws + 6291456 + 131072 + 2 * 786432);        // 811008 B

    hipFuncSetAttribute((const void*)gram2,
                        hipFuncAttributeMaxDynamicSharedMemorySize, SMEM_BYTES);

    prep<<<dim3(104, 8), dim3(256), 0, stream>>>(x, Wq, Wk, xt, wqb, wkb);
    pam_qk<<<dim3(32, 4), dim3(256), 0, stream>>>(xt, wqb, wkb, bq, bk, qbuf, kbuf);
    gram2<<<dim3(NG2), dim3(512), SMEM_BYTES, stream>>>(xt, out, ws2);
    energy_fin<<<dim3(656), dim3(256), 0, stream>>>(qbuf, kbuf, ws2, out);
}